// Round 6
// baseline (691.467 us; speedup 1.0000x reference)
//
#include <hip/hip_runtime.h>

// Problem constants (B,T,A,D,U) = (64, 2048, 512, 512, 512)
constexpr int U = 512;
constexpr int B = 64;
constexpr int T = 2048;
constexpr int A = 512;

typedef __attribute__((ext_vector_type(8))) short short8;   // 8 bf16 = 4 VGPRs (MFMA A/B frag)
typedef __attribute__((ext_vector_type(4))) float f32x4;    // MFMA C/D frag

__device__ __forceinline__ unsigned short f32_to_bf16(float f) {
    unsigned int b = __float_as_uint(f);
    unsigned int r = (b + 0x7FFFu + ((b >> 16) & 1u)) >> 16;
    return (unsigned short)r;
}

__device__ __forceinline__ float bf16_to_f32(short s) {
    return __uint_as_float(((unsigned int)(unsigned short)s) << 16);
}

__device__ __forceinline__ float fast_tanh(float x) {
    float e = exp2f(x * 2.885390081777927f);
    return (e - 1.0f) * __builtin_amdgcn_rcpf(e + 1.0f);
}

__device__ __forceinline__ float hard_sigmoid(float z) {
    return fminf(fmaxf(0.2f * z + 0.5f, 0.0f), 1.0f);
}

// ---------------------------------------------------------------------------
// K0: streaming fp32 -> bf16 convert of annotations (256 MB -> 128 MB).
// Pure bandwidth: 32 B read + 16 B write per thread-iter. grid 2048 x 256.
__global__ __launch_bounds__(256) void k_convert(const float* __restrict__ ann,
                                                 unsigned short* __restrict__ annb) {
    const size_t nchunks = (size_t)B * T * A / 8;           // 8.39M
    const size_t stride = (size_t)gridDim.x * blockDim.x;
    for (size_t c = (size_t)blockIdx.x * blockDim.x + threadIdx.x; c < nchunks; c += stride) {
        const float* src = ann + c * 8;
        f32x4 v0 = *(const f32x4*)src;
        f32x4 v1 = *(const f32x4*)(src + 4);
        short8 pk;
        pk[0] = (short)f32_to_bf16(v0.x);
        pk[1] = (short)f32_to_bf16(v0.y);
        pk[2] = (short)f32_to_bf16(v0.z);
        pk[3] = (short)f32_to_bf16(v0.w);
        pk[4] = (short)f32_to_bf16(v1.x);
        pk[5] = (short)f32_to_bf16(v1.y);
        pk[6] = (short)f32_to_bf16(v1.z);
        pk[7] = (short)f32_to_bf16(v1.w);
        *(short8*)(annb + c * 8) = pk;
    }
}

// ---------------------------------------------------------------------------
// K1a: split-K partials for S = bias_u + h @ kernel_w. grid 256 x 256.
__global__ __launch_bounds__(256) void k_prep_s(const float* __restrict__ h,
                                                const float* __restrict__ kw,
                                                float* __restrict__ Sp) {
    int b = blockIdx.x >> 2;
    int kc = blockIdx.x & 3;
    int u = threadIdx.x;
    const float* hb = h + b * U + kc * 128;
    const float* kwb = kw + (size_t)kc * 128 * U;
    float a0 = 0.f, a1 = 0.f;
#pragma unroll 4
    for (int k = 0; k < 128; ++k) {
        float hv = hb[k];
        a0 += hv * kwb[(size_t)k * U + u];
        a1 += hv * kwb[(size_t)k * U + u + 256];
    }
    float* p = Sp + ((size_t)kc * 64 + b) * U;
    p[u] = a0;
    p[u + 256] = a1;
}

// K1a2: S[b][u] = bias_u[u] + sum_kc Sp. grid 128 x 256
__global__ __launch_bounds__(256) void k_s_reduce(const float* __restrict__ Sp,
                                                  const float* __restrict__ bias,
                                                  float* __restrict__ S) {
    int gid = blockIdx.x * 256 + threadIdx.x;
    int b = gid >> 9, u = gid & 511;
    float s = bias[4 * U + u];
#pragma unroll
    for (int kc = 0; kc < 4; ++kc) s += Sp[((size_t)kc * 64 + b) * U + u];
    S[gid] = s;
}

// ---------------------------------------------------------------------------
// K1b: kut[u][a] = bf16(kernel_u[a][u]). grid 256 x 256
__global__ __launch_bounds__(256) void k_prep_kut(const float* __restrict__ ku,
                                                  unsigned short* __restrict__ kut) {
    __shared__ float tile[32][33];
    int a0 = (blockIdx.x >> 4) << 5;
    int u0 = (blockIdx.x & 15) << 5;
    int c = threadIdx.x & 31, r0 = threadIdx.x >> 5;
#pragma unroll
    for (int p = 0; p < 4; ++p) {
        int r = r0 + p * 8;
        tile[r][c] = ku[(a0 + r) * U + u0 + c];
    }
    __syncthreads();
#pragma unroll
    for (int p = 0; p < 4; ++p) {
        int r = r0 + p * 8;
        kut[(u0 + r) * A + a0 + c] = f32_to_bf16(tile[c][r]);
    }
}

// ---------------------------------------------------------------------------
// K1c: Wt[j][k] = bf16( W[k][j] ). grid (48, 64) x 256
__global__ __launch_bounds__(256) void k_prep_wt(const float* __restrict__ kern,
                                                 const float* __restrict__ rk,
                                                 unsigned short* __restrict__ Wt) {
    __shared__ float tile[32][33];
    int k0 = blockIdx.x << 5;
    int j0 = blockIdx.y << 5;
    int c = threadIdx.x & 31, r0 = threadIdx.x >> 5;
#pragma unroll
    for (int p = 0; p < 4; ++p) {
        int r = r0 + p * 8;
        int k = k0 + r;
        float val = (k < 1024) ? kern[k * 2048 + j0 + c]
                               : rk[(k - 1024) * 2048 + j0 + c];
        tile[r][c] = val;
    }
    __syncthreads();
#pragma unroll
    for (int p = 0; p < 4; ++p) {
        int r = r0 + p * 8;
        Wt[(size_t)(j0 + r) * 1536 + k0 + c] = f32_to_bf16(tile[c][r]);
    }
}

// ---------------------------------------------------------------------------
// K2: pure-bf16 128(M) x 256(N) MFMA GEMM + fused tanh/dot(v) epilogue.
// Both A (annb) and B (kut) staged via global_load_lds width=16 into
// XOR-chunk-swizzled LDS (conflict-free b128 reads, verified 0 conflicts
// in R5). No VALU converts, no in-loop stores -> the barrier drain only
// waits on the gll queue. Grid decode keeps nt-siblings on one XCD.
// grid 2048 x 256.
__global__ __launch_bounds__(256, 3) void k_gemm_et(const unsigned short* __restrict__ annb,
                                                    const unsigned short* __restrict__ kut,
                                                    const float* __restrict__ S,
                                                    const float* __restrict__ v,
                                                    float* __restrict__ etp) {
    __shared__ unsigned short As[128 * 64];   // 16 KB, swizzled (gll target)
    __shared__ unsigned short Bs[256 * 64];   // 32 KB, swizzled (gll target)
    __shared__ float red[4][64];

    const int tid = threadIdx.x;
    const int wave = tid >> 6;
    const int lane = tid & 63;
    const int lanelo = lane & 15;
    const int quad = lane >> 4;
    const int wm = wave >> 1, wn = wave & 1;

    const int bid = blockIdx.x;
    const int nt = (bid >> 3) & 1;
    const int mt = (bid & 7) | ((bid >> 4) << 3);   // 0..1023
    const int b = mt >> 4;                          // 16 m-tiles per batch
    const unsigned short* aBase = annb + (size_t)mt * 128 * A;
    const unsigned short* bBase = kut + (size_t)nt * 256 * A;

    f32x4 acc[4][8];
#pragma unroll
    for (int i = 0; i < 4; ++i)
#pragma unroll
        for (int j = 0; j < 8; ++j) acc[i][j] = {0.f, 0.f, 0.f, 0.f};

    for (int k0 = 0; k0 < A; k0 += 64) {
        // --- B staging: 32 KB, 8 gll issues/wave ---
#pragma unroll
        for (int p = 0; p < 8; ++p) {
            int seg = p * 4 + wave;                   // 1 KB segment
            int flat = seg * 1024 + lane * 16;        // byte offset in Bs
            int row = flat >> 7;                      // n-local 0..255
            int sc = (flat >> 4) & 7;                 // stored chunk slot
            int d = sc ^ (row & 7);                   // global chunk fetched
            __builtin_amdgcn_global_load_lds(
                (const __attribute__((address_space(1))) void*)(bBase + (size_t)row * A + k0 + d * 8),
                (__attribute__((address_space(3))) void*)((char*)Bs + seg * 1024),
                16, 0, 0);
        }
        // --- A staging: 16 KB, 4 gll issues/wave ---
#pragma unroll
        for (int p = 0; p < 4; ++p) {
            int seg = p * 4 + wave;                   // 1 KB segment
            int flat = seg * 1024 + lane * 16;
            int row = flat >> 7;                      // m-local 0..127
            int sc = (flat >> 4) & 7;
            int d = sc ^ (row & 7);
            __builtin_amdgcn_global_load_lds(
                (const __attribute__((address_space(1))) void*)(aBase + (size_t)row * A + k0 + d * 8),
                (__attribute__((address_space(3))) void*)((char*)As + seg * 1024),
                16, 0, 0);
        }
        __syncthreads();
        // --- inner: 2 K=32 steps, 64 MFMA/wave per iter ---
#pragma unroll
        for (int s = 0; s < 2; ++s) {
            int c = s * 4 + quad;
            short8 af[4];
#pragma unroll
            for (int mi = 0; mi < 4; ++mi) {
                int row = wm * 64 + mi * 16 + lanelo;
                af[mi] = *(const short8*)&As[row * 64 + ((c ^ (row & 7)) * 8)];
            }
            short8 bfr[8];
#pragma unroll
            for (int ni = 0; ni < 8; ++ni) {
                int rowb = wn * 128 + ni * 16 + lanelo;
                bfr[ni] = *(const short8*)&Bs[rowb * 64 + ((c ^ (rowb & 7)) * 8)];
            }
#pragma unroll
            for (int mi = 0; mi < 4; ++mi)
#pragma unroll
                for (int ni = 0; ni < 8; ++ni)
                    acc[mi][ni] = __builtin_amdgcn_mfma_f32_16x16x32_bf16(
                        af[mi], bfr[ni], acc[mi][ni], 0, 0, 0);
        }
        __syncthreads();
    }

    // Epilogue. C/D: col(n) = lane&15, row(m) = quad*4 + r (verified m89/m91).
    float rows[16];
#pragma unroll
    for (int i = 0; i < 16; ++i) rows[i] = 0.f;
#pragma unroll
    for (int ni = 0; ni < 8; ++ni) {
        int n = nt * 256 + wn * 128 + ni * 16 + lanelo;
        float sv = S[b * U + n];
        float vv = v[n];
#pragma unroll
        for (int mi = 0; mi < 4; ++mi)
#pragma unroll
            for (int r = 0; r < 4; ++r)
                rows[mi * 4 + r] += fast_tanh(acc[mi][ni][r] + sv) * vv;
    }
#pragma unroll
    for (int i = 0; i < 16; ++i) {
        rows[i] += __shfl_xor(rows[i], 1);
        rows[i] += __shfl_xor(rows[i], 2);
        rows[i] += __shfl_xor(rows[i], 4);
        rows[i] += __shfl_xor(rows[i], 8);
    }
    if (lanelo == 0) {
#pragma unroll
        for (int mi = 0; mi < 4; ++mi)
#pragma unroll
            for (int r = 0; r < 4; ++r)
                red[wave][mi * 16 + quad * 4 + r] = rows[mi * 4 + r];
    }
    __syncthreads();
    if (tid < 128) {
        int wmv = tid >> 6, ml = tid & 63;
        float sum = red[wmv * 2][ml] + red[wmv * 2 + 1][ml];
        etp[(size_t)nt * (1024 * 128) + (size_t)mt * 128 + tid] = sum;
    }
}

// ---------------------------------------------------------------------------
// K3: softmax over T per batch; sums the 2 etp N-partials inline. grid 64 x 256
__global__ __launch_bounds__(256) void k_softmax(const float* __restrict__ etp,
                                                 float* __restrict__ at) {
    __shared__ float sred[256];
    int b = blockIdx.x;
    const float* e = etp + b * T;
    float vals[8];
    float mx = -1e30f;
#pragma unroll
    for (int i = 0; i < 8; ++i) {
        int t = threadIdx.x + i * 256;
        float x = e[t] + e[131072 + t];
        vals[i] = x;
        mx = fmaxf(mx, x);
    }
    sred[threadIdx.x] = mx;
    __syncthreads();
    for (int s = 128; s > 0; s >>= 1) {
        if (threadIdx.x < s) sred[threadIdx.x] = fmaxf(sred[threadIdx.x], sred[threadIdx.x + s]);
        __syncthreads();
    }
    mx = sred[0];
    __syncthreads();
    float sum = 0.f;
#pragma unroll
    for (int i = 0; i < 8; ++i) {
        float x = exp2f((vals[i] - mx) * 1.4426950408889634f);
        vals[i] = x;
        sum += x;
    }
    sred[threadIdx.x] = sum;
    __syncthreads();
    for (int s = 128; s > 0; s >>= 1) {
        if (threadIdx.x < s) sred[threadIdx.x] += sred[threadIdx.x + s];
        __syncthreads();
    }
    float inv = 1.0f / sred[0];
#pragma unroll
    for (int i = 0; i < 8; ++i) at[b * T + threadIdx.x + i * 256] = vals[i] * inv;
}

// ---------------------------------------------------------------------------
// K4: context partials from bf16 annb (L3-resident). grid (64*8) x 256.
__global__ __launch_bounds__(256) void k_ctx_part(const float* __restrict__ at,
                                                  const unsigned short* __restrict__ annb,
                                                  float* __restrict__ part) {
    __shared__ float buf[4][512];
    int b = blockIdx.x >> 3;
    int tc = blockIdx.x & 7;
    int wave = threadIdx.x >> 6;
    int lane = threadIdx.x & 63;
    const unsigned short* ab = annb + ((size_t)b * T + tc * 256) * A + lane * 8;
    const float* atb = at + b * T + tc * 256;
    float acc[8];
#pragma unroll
    for (int i = 0; i < 8; ++i) acc[i] = 0.f;
    for (int t = wave; t < 256; t += 4) {
        float w = atb[t];
        short8 rv = *(const short8*)(ab + (size_t)t * A);
#pragma unroll
        for (int i = 0; i < 8; ++i) acc[i] += w * bf16_to_f32(rv[i]);
    }
#pragma unroll
    for (int i = 0; i < 8; ++i) buf[wave][lane * 8 + i] = acc[i];
    __syncthreads();
    int a2 = threadIdx.x << 1;
    float s0 = buf[0][a2] + buf[1][a2] + buf[2][a2] + buf[3][a2];
    float s1 = buf[0][a2 + 1] + buf[1][a2 + 1] + buf[2][a2 + 1] + buf[3][a2 + 1];
    float* p = part + ((size_t)b * 8 + tc) * A;
    p[a2] = s0;
    p[a2 + 1] = s1;
}

// ---------------------------------------------------------------------------
// K5: reduce partials -> context. grid 64 x 256
__global__ __launch_bounds__(256) void k_ctx_reduce(const float* __restrict__ part,
                                                    float* __restrict__ ctx) {
    int b = blockIdx.x;
    for (int a = threadIdx.x; a < A; a += 256) {
        float s = 0.f;
#pragma unroll
        for (int c = 0; c < 8; ++c) s += part[((size_t)b * 8 + c) * A + a];
        ctx[b * A + a] = s;
    }
}

// ---------------------------------------------------------------------------
// K5b: xb[b][0:1536] = bf16([inputs | ctx | h]). grid (6, 64) x 256
__global__ __launch_bounds__(256) void k_prep_xb(const float* __restrict__ inputs,
                                                 const float* __restrict__ ctx,
                                                 const float* __restrict__ h,
                                                 unsigned short* __restrict__ xb) {
    int b = blockIdx.y;
    int k = blockIdx.x * 256 + threadIdx.x;
    float val;
    if (k < 512) val = inputs[b * 512 + k];
    else if (k < 1024) val = ctx[b * 512 + (k - 512)];
    else val = h[b * 512 + (k - 1024)];
    xb[b * 1536 + k] = f32_to_bf16(val);
}

// ---------------------------------------------------------------------------
// K6a: z-GEMM, split-K MFMA. grid 256 x 256.
__global__ __launch_bounds__(256) void k_zgemm(const unsigned short* __restrict__ xb,
                                               const unsigned short* __restrict__ Wt,
                                               float* __restrict__ zpart) {
    const int kc = blockIdx.x & 7;
    const int nt = blockIdx.x >> 3;
    const int wave = threadIdx.x >> 6;
    const int lane = threadIdx.x & 63;
    const int lanelo = lane & 15;
    const int quad = lane >> 4;

    const int n = nt * 64 + wave * 16 + lanelo;
    const unsigned short* bp = Wt + (size_t)n * 1536 + kc * 192 + quad * 8;
    const unsigned short* ap = xb + (size_t)lanelo * 1536 + kc * 192 + quad * 8;

    f32x4 acc[4];
#pragma unroll
    for (int i = 0; i < 4; ++i) acc[i] = {0.f, 0.f, 0.f, 0.f};

#pragma unroll
    for (int ks = 0; ks < 6; ++ks) {
        short8 bfrag = *(const short8*)(bp + ks * 32);
#pragma unroll
        for (int mi = 0; mi < 4; ++mi) {
            short8 afrag = *(const short8*)(ap + (size_t)mi * 16 * 1536 + ks * 32);
            acc[mi] = __builtin_amdgcn_mfma_f32_16x16x32_bf16(afrag, bfrag, acc[mi], 0, 0, 0);
        }
    }

    float* p = zpart + (size_t)kc * 64 * 2048;
#pragma unroll
    for (int mi = 0; mi < 4; ++mi)
#pragma unroll
        for (int r = 0; r < 4; ++r) {
            int m = mi * 16 + quad * 4 + r;
            p[(size_t)m * 2048 + n] = acc[mi][r];
        }
}

// ---------------------------------------------------------------------------
// K6b: combine partials + bias -> gates -> h_new. grid 128 x 256
__global__ __launch_bounds__(256) void k_gates(const float* __restrict__ zpart,
                                               const float* __restrict__ bias,
                                               const float* __restrict__ c,
                                               float* __restrict__ hnew) {
    int gid = blockIdx.x * 256 + threadIdx.x;
    int b = gid >> 9;
    int u = gid & 511;
    float z[4];
#pragma unroll
    for (int g = 0; g < 4; ++g) {
        int j = (g << 9) + u;
        float s = bias[j];
#pragma unroll
        for (int kc = 0; kc < 8; ++kc)
            s += zpart[((size_t)kc * 64 + b) * 2048 + j];
        z[g] = s;
    }
    float ig = hard_sigmoid(z[0]);
    float fg = hard_sigmoid(z[1]);
    float cn = fg * c[b * 512 + u] + ig * fast_tanh(z[2]);
    float og = hard_sigmoid(z[3]);
    hnew[b * 512 + u] = og * fast_tanh(cn);
}

// ---------------------------------------------------------------------------
extern "C" void kernel_launch(void* const* d_in, const int* in_sizes, int n_in,
                              void* d_out, int out_size, void* d_ws, size_t ws_size,
                              hipStream_t stream) {
    const float* inputs = (const float*)d_in[0];
    const float* h      = (const float*)d_in[1];
    const float* c      = (const float*)d_in[2];
    const float* ann    = (const float*)d_in[3];
    const float* kern   = (const float*)d_in[4];
    const float* rk     = (const float*)d_in[5];
    const float* bias   = (const float*)d_in[6];
    const float* ku     = (const float*)d_in[7];
    const float* kw     = (const float*)d_in[8];
    const float* kv     = (const float*)d_in[9];

    // ws layout (bytes):
    //   S      @ 0         131072
    //   kut    @ 131072    524288
    //   etp    @ 655360    1048576   (2 N-partials x 131072 fp32)
    //   at     @ 1703936   524288
    //   part   @ 2228224   1048576   (ctx partials, 8 chunks; Sp alias early)
    //   ctx    @ 3276800   131072
    //   xb     @ 3407872   196608
    //   Wt     @ 3604480   6291456
    //   zpart  @ 9895936   4194304
    //   annb   @ 16777216  134217728 (bf16 copy of annotations, L3-resident)
    char* ws = (char*)d_ws;
    float*          S     = (float*)(ws + 0);
    unsigned short* kut   = (unsigned short*)(ws + 131072);
    float*          etp   = (float*)(ws + 655360);
    float*          at    = (float*)(ws + 1703936);
    float*          part  = (float*)(ws + 2228224);
    float*          Sp    = (float*)(ws + 2228224);   // alias: consumed before part written
    float*          ctx   = (float*)(ws + 3276800);
    unsigned short* xb    = (unsigned short*)(ws + 3407872);
    unsigned short* Wt    = (unsigned short*)(ws + 3604480);
    float*          zpart = (float*)(ws + 9895936);
    unsigned short* annb  = (unsigned short*)(ws + 16777216);
    float*          hnew  = (float*)d_out;

    k_convert<<<2048, 256, 0, stream>>>(ann, annb);
    k_prep_wt<<<dim3(48, 64), 256, 0, stream>>>(kern, rk, Wt);
    k_prep_kut<<<256, 256, 0, stream>>>(ku, kut);
    k_prep_s<<<256, 256, 0, stream>>>(h, kw, Sp);
    k_s_reduce<<<128, 256, 0, stream>>>(Sp, bias, S);
    k_gemm_et<<<2048, 256, 0, stream>>>(annb, kut, S, kv, etp);
    k_softmax<<<64, 256, 0, stream>>>(etp, at);
    k_ctx_part<<<64 * 8, 256, 0, stream>>>(at, annb, part);
    k_ctx_reduce<<<64, 256, 0, stream>>>(part, ctx);
    k_prep_xb<<<dim3(6, 64), 256, 0, stream>>>(inputs, ctx, h, xb);
    k_zgemm<<<256, 256, 0, stream>>>(xb, Wt, zpart);
    k_gates<<<128, 256, 0, stream>>>(zpart, bias, c, hnew);
}

// Round 7
// 515.573 us; speedup vs baseline: 1.3412x; 1.3412x over previous
//
#include <hip/hip_runtime.h>

// Problem constants (B,T,A,D,U) = (64, 2048, 512, 512, 512)
constexpr int U = 512;
constexpr int B = 64;
constexpr int T = 2048;
constexpr int A = 512;

typedef __attribute__((ext_vector_type(8))) short short8;   // 8 bf16 = 4 VGPRs (MFMA A/B frag)
typedef __attribute__((ext_vector_type(4))) float f32x4;    // MFMA C/D frag

__device__ __forceinline__ unsigned short f32_to_bf16(float f) {
    unsigned int b = __float_as_uint(f);
    unsigned int r = (b + 0x7FFFu + ((b >> 16) & 1u)) >> 16;
    return (unsigned short)r;
}

__device__ __forceinline__ float fast_tanh(float x) {
    float e = exp2f(x * 2.885390081777927f);
    return (e - 1.0f) * __builtin_amdgcn_rcpf(e + 1.0f);
}

__device__ __forceinline__ float hard_sigmoid(float z) {
    return fminf(fmaxf(0.2f * z + 0.5f, 0.0f), 1.0f);
}

// ---------------------------------------------------------------------------
// K1a: split-K partials for S = bias_u + h @ kernel_w. grid 256 x 256.
__global__ __launch_bounds__(256) void k_prep_s(const float* __restrict__ h,
                                                const float* __restrict__ kw,
                                                float* __restrict__ Sp) {
    int b = blockIdx.x >> 2;
    int kc = blockIdx.x & 3;
    int u = threadIdx.x;
    const float* hb = h + b * U + kc * 128;
    const float* kwb = kw + (size_t)kc * 128 * U;
    float a0 = 0.f, a1 = 0.f;
#pragma unroll 4
    for (int k = 0; k < 128; ++k) {
        float hv = hb[k];
        a0 += hv * kwb[(size_t)k * U + u];
        a1 += hv * kwb[(size_t)k * U + u + 256];
    }
    float* p = Sp + ((size_t)kc * 64 + b) * U;
    p[u] = a0;
    p[u + 256] = a1;
}

// K1a2: S[b][u] = bias_u[u] + sum_kc Sp. grid 128 x 256
__global__ __launch_bounds__(256) void k_s_reduce(const float* __restrict__ Sp,
                                                  const float* __restrict__ bias,
                                                  float* __restrict__ S) {
    int gid = blockIdx.x * 256 + threadIdx.x;
    int b = gid >> 9, u = gid & 511;
    float s = bias[4 * U + u];
#pragma unroll
    for (int kc = 0; kc < 4; ++kc) s += Sp[((size_t)kc * 64 + b) * U + u];
    S[gid] = s;
}

// ---------------------------------------------------------------------------
// K1b: kut[u][a] = bf16(kernel_u[a][u]). grid 256 x 256
__global__ __launch_bounds__(256) void k_prep_kut(const float* __restrict__ ku,
                                                  unsigned short* __restrict__ kut) {
    __shared__ float tile[32][33];
    int a0 = (blockIdx.x >> 4) << 5;
    int u0 = (blockIdx.x & 15) << 5;
    int c = threadIdx.x & 31, r0 = threadIdx.x >> 5;
#pragma unroll
    for (int p = 0; p < 4; ++p) {
        int r = r0 + p * 8;
        tile[r][c] = ku[(a0 + r) * U + u0 + c];
    }
    __syncthreads();
#pragma unroll
    for (int p = 0; p < 4; ++p) {
        int r = r0 + p * 8;
        kut[(u0 + r) * A + a0 + c] = f32_to_bf16(tile[c][r]);
    }
}

// ---------------------------------------------------------------------------
// K1c: Wt[j][k] = bf16( W[k][j] ). grid (48, 64) x 256
__global__ __launch_bounds__(256) void k_prep_wt(const float* __restrict__ kern,
                                                 const float* __restrict__ rk,
                                                 unsigned short* __restrict__ Wt) {
    __shared__ float tile[32][33];
    int k0 = blockIdx.x << 5;
    int j0 = blockIdx.y << 5;
    int c = threadIdx.x & 31, r0 = threadIdx.x >> 5;
#pragma unroll
    for (int p = 0; p < 4; ++p) {
        int r = r0 + p * 8;
        int k = k0 + r;
        float val = (k < 1024) ? kern[k * 2048 + j0 + c]
                               : rk[(k - 1024) * 2048 + j0 + c];
        tile[r][c] = val;
    }
    __syncthreads();
#pragma unroll
    for (int p = 0; p < 4; ++p) {
        int r = r0 + p * 8;
        Wt[(size_t)(j0 + r) * 1536 + k0 + c] = f32_to_bf16(tile[c][r]);
    }
}

// ---------------------------------------------------------------------------
// K2: full-N MFMA GEMM + fused tanh/dot(v) -> et, ONE fp32 pass over ann.
// Block: 256 thr / 4 waves; tile M=64 x N=512 (all u); wave-tile 64x128
// (acc 4x8). K=512 in BK=64 iters. A: fp32 register-prefetched one iter
// ahead (loads in flight across the MFMA loop), converted once, ds_write
// into swizzled As (8 KB). B: kut via global_load_lds w=16 into swizzled
// Bs (64 KB, L2-resident source). No annb intermediate, no writebacks,
// et written whole (no partials). 2 blocks/CU (73 KB LDS, ~220 VGPR).
// grid 2048 x 256.
__global__ __launch_bounds__(256, 2) void k_gemm_et(const float* __restrict__ ann,
                                                    const unsigned short* __restrict__ kut,
                                                    const float* __restrict__ S,
                                                    const float* __restrict__ v,
                                                    float* __restrict__ et) {
    __shared__ unsigned short As[64 * 64];    // 8 KB, swizzled
    __shared__ unsigned short Bs[512 * 64];   // 64 KB, swizzled (gll target)
    __shared__ float red[4][64];

    const int tid = threadIdx.x;
    const int wave = tid >> 6;
    const int lane = tid & 63;
    const int lanelo = lane & 15;
    const int quad = lane >> 4;
    const int wn = wave;                 // wave-tile: all M, n-slice wn*128

    const int mt = blockIdx.x;           // 0..2047
    const int b = mt >> 5;               // 32 m-tiles per batch
    const int t0 = (mt & 31) << 6;
    const float* aBase = ann + (size_t)mt * 64 * A;

    f32x4 acc[4][8];
#pragma unroll
    for (int i = 0; i < 4; ++i)
#pragma unroll
        for (int j = 0; j < 8; ++j) acc[i][j] = {0.f, 0.f, 0.f, 0.f};

    // A register prefetch buffers: 2 passes x 2 float4
    f32x4 pv[4];
    const int rowA = tid >> 3;           // pass q adds 32
    const int c8A = tid & 7;

#pragma unroll
    for (int q = 0; q < 2; ++q) {
        const float* src = aBase + (size_t)(q * 32 + rowA) * A + 0 + c8A * 8;
        pv[q * 2] = *(const f32x4*)src;
        pv[q * 2 + 1] = *(const f32x4*)(src + 4);
    }

    for (int k0 = 0; k0 < A; k0 += 64) {
        // --- B staging: 64 KB, 16 gll issues/thread ---
#pragma unroll
        for (int p = 0; p < 16; ++p) {
            int seg = p * 4 + wave;                   // 1 KB segment
            int flat = seg * 1024 + lane * 16;        // byte offset in Bs
            int row = flat >> 7;                      // n-local 0..511
            int sc = (flat >> 4) & 7;                 // stored chunk slot
            int d = sc ^ (row & 7);                   // global chunk fetched
            __builtin_amdgcn_global_load_lds(
                (const __attribute__((address_space(1))) void*)(kut + (size_t)row * A + k0 + d * 8),
                (__attribute__((address_space(3))) void*)((char*)Bs + seg * 1024),
                16, 0, 0);
        }
        // --- A: convert prefetched regs, swizzled 16B LDS store ---
#pragma unroll
        for (int q = 0; q < 2; ++q) {
            int row = q * 32 + rowA;
            f32x4 v0 = pv[q * 2], v1 = pv[q * 2 + 1];
            short8 pk;
            pk[0] = (short)f32_to_bf16(v0.x);
            pk[1] = (short)f32_to_bf16(v0.y);
            pk[2] = (short)f32_to_bf16(v0.z);
            pk[3] = (short)f32_to_bf16(v0.w);
            pk[4] = (short)f32_to_bf16(v1.x);
            pk[5] = (short)f32_to_bf16(v1.y);
            pk[6] = (short)f32_to_bf16(v1.z);
            pk[7] = (short)f32_to_bf16(v1.w);
            *(short8*)&As[row * 64 + ((c8A ^ (row & 7)) * 8)] = pk;
        }
        __syncthreads();
        // --- prefetch next A tile into regs (in flight across MFMAs) ---
        if (k0 + 64 < A) {
#pragma unroll
            for (int q = 0; q < 2; ++q) {
                const float* src = aBase + (size_t)(q * 32 + rowA) * A + (k0 + 64) + c8A * 8;
                pv[q * 2] = *(const f32x4*)src;
                pv[q * 2 + 1] = *(const f32x4*)(src + 4);
            }
        }
        // --- inner: 2 K=32 steps, 64 MFMA/wave per iter ---
#pragma unroll
        for (int s = 0; s < 2; ++s) {
            int c = s * 4 + quad;
            short8 af[4];
#pragma unroll
            for (int mi = 0; mi < 4; ++mi) {
                int row = mi * 16 + lanelo;
                af[mi] = *(const short8*)&As[row * 64 + ((c ^ (row & 7)) * 8)];
            }
            short8 bfr[8];
#pragma unroll
            for (int ni = 0; ni < 8; ++ni) {
                int rowb = wn * 128 + ni * 16 + lanelo;
                bfr[ni] = *(const short8*)&Bs[rowb * 64 + ((c ^ (rowb & 7)) * 8)];
            }
#pragma unroll
            for (int mi = 0; mi < 4; ++mi)
#pragma unroll
                for (int ni = 0; ni < 8; ++ni)
                    acc[mi][ni] = __builtin_amdgcn_mfma_f32_16x16x32_bf16(
                        af[mi], bfr[ni], acc[mi][ni], 0, 0, 0);
        }
        __syncthreads();
    }

    // Epilogue. C/D: col(n) = lane&15, row(m) = quad*4 + r (verified m89/m91).
    float rows[16];
#pragma unroll
    for (int i = 0; i < 16; ++i) rows[i] = 0.f;
#pragma unroll
    for (int ni = 0; ni < 8; ++ni) {
        int u = wn * 128 + ni * 16 + lanelo;
        float sv = S[b * U + u];
        float vv = v[u];
#pragma unroll
        for (int mi = 0; mi < 4; ++mi)
#pragma unroll
            for (int r = 0; r < 4; ++r)
                rows[mi * 4 + r] += fast_tanh(acc[mi][ni][r] + sv) * vv;
    }
#pragma unroll
    for (int i = 0; i < 16; ++i) {
        rows[i] += __shfl_xor(rows[i], 1);
        rows[i] += __shfl_xor(rows[i], 2);
        rows[i] += __shfl_xor(rows[i], 4);
        rows[i] += __shfl_xor(rows[i], 8);
    }
    if (lanelo == 0) {
#pragma unroll
        for (int mi = 0; mi < 4; ++mi)
#pragma unroll
            for (int r = 0; r < 4; ++r)
                red[wave][mi * 16 + quad * 4 + r] = rows[mi * 4 + r];
    }
    __syncthreads();
    if (tid < 64) {
        float sum = red[0][tid] + red[1][tid] + red[2][tid] + red[3][tid];
        et[b * T + t0 + tid] = sum;
    }
}

// ---------------------------------------------------------------------------
// K3: softmax over T per batch. grid 64 x 256
__global__ __launch_bounds__(256) void k_softmax(const float* __restrict__ et,
                                                 float* __restrict__ at) {
    __shared__ float sred[256];
    int b = blockIdx.x;
    const float* e = et + b * T;
    float vals[8];
    float mx = -1e30f;
#pragma unroll
    for (int i = 0; i < 8; ++i) {
        int t = threadIdx.x + i * 256;
        float x = e[t];
        vals[i] = x;
        mx = fmaxf(mx, x);
    }
    sred[threadIdx.x] = mx;
    __syncthreads();
    for (int s = 128; s > 0; s >>= 1) {
        if (threadIdx.x < s) sred[threadIdx.x] = fmaxf(sred[threadIdx.x], sred[threadIdx.x + s]);
        __syncthreads();
    }
    mx = sred[0];
    __syncthreads();
    float sum = 0.f;
#pragma unroll
    for (int i = 0; i < 8; ++i) {
        float x = exp2f((vals[i] - mx) * 1.4426950408889634f);
        vals[i] = x;
        sum += x;
    }
    sred[threadIdx.x] = sum;
    __syncthreads();
    for (int s = 128; s > 0; s >>= 1) {
        if (threadIdx.x < s) sred[threadIdx.x] += sred[threadIdx.x + s];
        __syncthreads();
    }
    float inv = 1.0f / sred[0];
#pragma unroll
    for (int i = 0; i < 8; ++i) at[b * T + threadIdx.x + i * 256] = vals[i] * inv;
}

// ---------------------------------------------------------------------------
// K4: context partials, fp32 ann, 16 B/lane, two t's in flight per block.
// grid (64*8) x 256.
__global__ __launch_bounds__(256) void k_ctx_part(const float* __restrict__ at,
                                                  const float* __restrict__ ann,
                                                  float* __restrict__ part) {
    __shared__ float buf[2][512];
    int b = blockIdx.x >> 3;
    int tc = blockIdx.x & 7;
    int half = threadIdx.x >> 7;        // 0..1
    int a4 = (threadIdx.x & 127) << 2;  // 0,4,...,508
    const float* annb = ann + ((size_t)b * T + tc * 256) * A;
    const float* atb = at + b * T + tc * 256;
    f32x4 acc = {0.f, 0.f, 0.f, 0.f};
    for (int t = half; t < 256; t += 2) {
        float w = atb[t];
        f32x4 rv = *(const f32x4*)(annb + (size_t)t * A + a4);
        acc.x += w * rv.x;
        acc.y += w * rv.y;
        acc.z += w * rv.z;
        acc.w += w * rv.w;
    }
    *(f32x4*)&buf[half][a4] = acc;
    __syncthreads();
    int a2 = threadIdx.x << 1;
    float s0 = buf[0][a2] + buf[1][a2];
    float s1 = buf[0][a2 + 1] + buf[1][a2 + 1];
    float* p = part + ((size_t)b * 8 + tc) * A;
    p[a2] = s0;
    p[a2 + 1] = s1;
}

// ---------------------------------------------------------------------------
// K5: reduce partials -> context. grid 64 x 256
__global__ __launch_bounds__(256) void k_ctx_reduce(const float* __restrict__ part,
                                                    float* __restrict__ ctx) {
    int b = blockIdx.x;
    for (int a = threadIdx.x; a < A; a += 256) {
        float s = 0.f;
#pragma unroll
        for (int c = 0; c < 8; ++c) s += part[((size_t)b * 8 + c) * A + a];
        ctx[b * A + a] = s;
    }
}

// ---------------------------------------------------------------------------
// K5b: xb[b][0:1536] = bf16([inputs | ctx | h]). grid (6, 64) x 256
__global__ __launch_bounds__(256) void k_prep_xb(const float* __restrict__ inputs,
                                                 const float* __restrict__ ctx,
                                                 const float* __restrict__ h,
                                                 unsigned short* __restrict__ xb) {
    int b = blockIdx.y;
    int k = blockIdx.x * 256 + threadIdx.x;
    float val;
    if (k < 512) val = inputs[b * 512 + k];
    else if (k < 1024) val = ctx[b * 512 + (k - 512)];
    else val = h[b * 512 + (k - 1024)];
    xb[b * 1536 + k] = f32_to_bf16(val);
}

// ---------------------------------------------------------------------------
// K6a: z-GEMM, split-K MFMA. grid 256 x 256.
__global__ __launch_bounds__(256) void k_zgemm(const unsigned short* __restrict__ xb,
                                               const unsigned short* __restrict__ Wt,
                                               float* __restrict__ zpart) {
    const int kc = blockIdx.x & 7;
    const int nt = blockIdx.x >> 3;
    const int wave = threadIdx.x >> 6;
    const int lane = threadIdx.x & 63;
    const int lanelo = lane & 15;
    const int quad = lane >> 4;

    const int n = nt * 64 + wave * 16 + lanelo;
    const unsigned short* bp = Wt + (size_t)n * 1536 + kc * 192 + quad * 8;
    const unsigned short* ap = xb + (size_t)lanelo * 1536 + kc * 192 + quad * 8;

    f32x4 acc[4];
#pragma unroll
    for (int i = 0; i < 4; ++i) acc[i] = {0.f, 0.f, 0.f, 0.f};

#pragma unroll
    for (int ks = 0; ks < 6; ++ks) {
        short8 bfrag = *(const short8*)(bp + ks * 32);
#pragma unroll
        for (int mi = 0; mi < 4; ++mi) {
            short8 afrag = *(const short8*)(ap + (size_t)mi * 16 * 1536 + ks * 32);
            acc[mi] = __builtin_amdgcn_mfma_f32_16x16x32_bf16(afrag, bfrag, acc[mi], 0, 0, 0);
        }
    }

    float* p = zpart + (size_t)kc * 64 * 2048;
#pragma unroll
    for (int mi = 0; mi < 4; ++mi)
#pragma unroll
        for (int r = 0; r < 4; ++r) {
            int m = mi * 16 + quad * 4 + r;
            p[(size_t)m * 2048 + n] = acc[mi][r];
        }
}

// ---------------------------------------------------------------------------
// K6b: combine partials + bias -> gates -> h_new. grid 128 x 256
__global__ __launch_bounds__(256) void k_gates(const float* __restrict__ zpart,
                                               const float* __restrict__ bias,
                                               const float* __restrict__ c,
                                               float* __restrict__ hnew) {
    int gid = blockIdx.x * 256 + threadIdx.x;
    int b = gid >> 9;
    int u = gid & 511;
    float z[4];
#pragma unroll
    for (int g = 0; g < 4; ++g) {
        int j = (g << 9) + u;
        float s = bias[j];
#pragma unroll
        for (int kc = 0; kc < 8; ++kc)
            s += zpart[((size_t)kc * 64 + b) * 2048 + j];
        z[g] = s;
    }
    float ig = hard_sigmoid(z[0]);
    float fg = hard_sigmoid(z[1]);
    float cn = fg * c[b * 512 + u] + ig * fast_tanh(z[2]);
    float og = hard_sigmoid(z[3]);
    hnew[b * 512 + u] = og * fast_tanh(cn);
}

// ---------------------------------------------------------------------------
extern "C" void kernel_launch(void* const* d_in, const int* in_sizes, int n_in,
                              void* d_out, int out_size, void* d_ws, size_t ws_size,
                              hipStream_t stream) {
    const float* inputs = (const float*)d_in[0];
    const float* h      = (const float*)d_in[1];
    const float* c      = (const float*)d_in[2];
    const float* ann    = (const float*)d_in[3];
    const float* kern   = (const float*)d_in[4];
    const float* rk     = (const float*)d_in[5];
    const float* bias   = (const float*)d_in[6];
    const float* ku     = (const float*)d_in[7];
    const float* kw     = (const float*)d_in[8];
    const float* kv     = (const float*)d_in[9];

    // ws layout (bytes):
    //   S      @ 0         131072
    //   kut    @ 131072    524288
    //   et     @ 655360    524288
    //   at     @ 1703936   524288
    //   part   @ 2228224   1048576   (ctx partials, 8 chunks; Sp alias early)
    //   ctx    @ 3276800   131072
    //   xb     @ 3407872   196608
    //   Wt     @ 3604480   6291456
    //   zpart  @ 9895936   4194304
    char* ws = (char*)d_ws;
    float*          S     = (float*)(ws + 0);
    unsigned short* kut   = (unsigned short*)(ws + 131072);
    float*          et    = (float*)(ws + 655360);
    float*          at    = (float*)(ws + 1703936);
    float*          part  = (float*)(ws + 2228224);
    float*          Sp    = (float*)(ws + 2228224);   // alias: consumed before part written
    float*          ctx   = (float*)(ws + 3276800);
    unsigned short* xb    = (unsigned short*)(ws + 3407872);
    unsigned short* Wt    = (unsigned short*)(ws + 3604480);
    float*          zpart = (float*)(ws + 9895936);
    float*          hnew  = (float*)d_out;

    k_prep_wt<<<dim3(48, 64), 256, 0, stream>>>(kern, rk, Wt);
    k_prep_kut<<<256, 256, 0, stream>>>(ku, kut);
    k_prep_s<<<256, 256, 0, stream>>>(h, kw, Sp);
    k_s_reduce<<<128, 256, 0, stream>>>(Sp, bias, S);
    k_gemm_et<<<2048, 256, 0, stream>>>(ann, kut, S, kv, et);
    k_softmax<<<64, 256, 0, stream>>>(et, at);
    k_ctx_part<<<64 * 8, 256, 0, stream>>>(at, ann, part);
    k_ctx_reduce<<<64, 256, 0, stream>>>(part, ctx);
    k_prep_xb<<<dim3(6, 64), 256, 0, stream>>>(inputs, ctx, h, xb);
    k_zgemm<<<256, 256, 0, stream>>>(xb, Wt, zpart);
    k_gates<<<128, 256, 0, stream>>>(zpart, bias, c, hnew);
}